// Round 1
// baseline (249.285 us; speedup 1.0000x reference)
//
#include <hip/hip_runtime.h>

// Problem constants (from reference setup_inputs):
//   input_tensor: (32, 64, 64, 64)  fp32   -- d_in[0]
//   pool_input:   (32, 128, 128, 64) fp32  -- d_in[1]
//   out:          (32, 128, 128, 64) fp32
// POOL = STRIDES = (2,2) -> non-overlapping windows -> out[b,h,w,c] =
//   (pool_input[b,h,w,c] == max of its 2x2 window) ? input_tensor[b,h/2,w/2,c] : 0

#define BB 32
#define HH 128
#define WW 128
#define CC 64
#define HO 64
#define WO 64
#define C4 (CC / 4)          // 16 float4 per channel row
#define WC4 (WW * C4)        // float4 stride of one pool row = 2048

__global__ __launch_bounds__(256) void unpool2d_kernel(
    const float4* __restrict__ input,  // (B,HO,WO,C4)
    const float4* __restrict__ pool,   // (B,H,W,C4)
    float4* __restrict__ out)          // (B,H,W,C4)
{
    const int idx = blockIdx.x * blockDim.x + threadIdx.x;
    // idx maps (b, i, j, c4) with c4 fastest: idx = ((b*HO + i)*WO + j)*C4 + c4
    const int c4 = idx & (C4 - 1);
    const int j  = (idx >> 4) & (WO - 1);
    const int i  = (idx >> 10) & (HO - 1);
    const int b  = idx >> 16;

    // Base float4 offset of window's top-left element in pool/out.
    const int base = ((b * HH + 2 * i) * WW + 2 * j) * C4 + c4;

    const float4 p00 = pool[base];
    const float4 p01 = pool[base + C4];
    const float4 p10 = pool[base + WC4];
    const float4 p11 = pool[base + WC4 + C4];

    float4 m;
    m.x = fmaxf(fmaxf(p00.x, p01.x), fmaxf(p10.x, p11.x));
    m.y = fmaxf(fmaxf(p00.y, p01.y), fmaxf(p10.y, p11.y));
    m.z = fmaxf(fmaxf(p00.z, p01.z), fmaxf(p10.z, p11.z));
    m.w = fmaxf(fmaxf(p00.w, p01.w), fmaxf(p10.w, p11.w));

    const float4 v = input[idx];  // flat idx == input_tensor float4 index

    float4 o;
    o.x = (p00.x == m.x) ? v.x : 0.0f;
    o.y = (p00.y == m.y) ? v.y : 0.0f;
    o.z = (p00.z == m.z) ? v.z : 0.0f;
    o.w = (p00.w == m.w) ? v.w : 0.0f;
    out[base] = o;

    o.x = (p01.x == m.x) ? v.x : 0.0f;
    o.y = (p01.y == m.y) ? v.y : 0.0f;
    o.z = (p01.z == m.z) ? v.z : 0.0f;
    o.w = (p01.w == m.w) ? v.w : 0.0f;
    out[base + C4] = o;

    o.x = (p10.x == m.x) ? v.x : 0.0f;
    o.y = (p10.y == m.y) ? v.y : 0.0f;
    o.z = (p10.z == m.z) ? v.z : 0.0f;
    o.w = (p10.w == m.w) ? v.w : 0.0f;
    out[base + WC4] = o;

    o.x = (p11.x == m.x) ? v.x : 0.0f;
    o.y = (p11.y == m.y) ? v.y : 0.0f;
    o.z = (p11.z == m.z) ? v.z : 0.0f;
    o.w = (p11.w == m.w) ? v.w : 0.0f;
    out[base + WC4 + C4] = o;
}

extern "C" void kernel_launch(void* const* d_in, const int* in_sizes, int n_in,
                              void* d_out, int out_size, void* d_ws, size_t ws_size,
                              hipStream_t stream) {
    const float4* input = (const float4*)d_in[0];  // input_tensor (32,64,64,64)
    const float4* pool  = (const float4*)d_in[1];  // pool_input (32,128,128,64)
    float4* out = (float4*)d_out;

    const int total = BB * HO * WO * C4;  // 2,097,152 threads
    const int block = 256;
    const int grid = total / block;       // 8192 blocks
    unpool2d_kernel<<<grid, block, 0, stream>>>(input, pool, out);
}

// Round 2
// 237.703 us; speedup vs baseline: 1.0487x; 1.0487x over previous
//
#include <hip/hip_runtime.h>

// input_tensor: (32, 64, 64, 64) fp32  -- d_in[0]
// pool_input:   (32, 128, 128, 64) fp32 -- d_in[1]
// out:          (32, 128, 128, 64) fp32
// POOL == STRIDES == (2,2): non-overlapping windows ->
//   out[b,h,w,c] = (pool[b,h,w,c] == window max) ? input[b,h/2,w/2,c] : 0
//
// R1: 2 windows per thread (batch-split), 10 independent loads issued up
// front (2x MLP per wave), non-temporal loads/stores (pure streaming).

#define BB 32
#define HH 128
#define WW 128
#define CC 64
#define HO 64
#define WO 64
#define C4 (CC / 4)          // 16 float4 per (b,h,w)
#define WC4 (WW * C4)        // 2048 float4 per pool row
#define HALF_N (16 * HO * WO * C4)        // 1,048,576 threads (b = 0..15)
#define POOL_HALF (16 * HH * WW * C4)     // float4 offset between b and b+16 in pool

typedef float v4 __attribute__((ext_vector_type(4)));

__device__ __forceinline__ v4 vmax4(v4 a, v4 b) {
    v4 r;
    r.x = fmaxf(a.x, b.x); r.y = fmaxf(a.y, b.y);
    r.z = fmaxf(a.z, b.z); r.w = fmaxf(a.w, b.w);
    return r;
}

__device__ __forceinline__ v4 vsel(v4 p, v4 m, v4 v) {
    v4 r;
    r.x = (p.x == m.x) ? v.x : 0.0f;
    r.y = (p.y == m.y) ? v.y : 0.0f;
    r.z = (p.z == m.z) ? v.z : 0.0f;
    r.w = (p.w == m.w) ? v.w : 0.0f;
    return r;
}

__global__ __launch_bounds__(256) void unpool2d_kernel(
    const v4* __restrict__ input,  // (B,HO,WO,C4)
    const v4* __restrict__ pool,   // (B,H,W,C4)
    v4* __restrict__ out)          // (B,H,W,C4)
{
    const int t = blockIdx.x * blockDim.x + threadIdx.x;   // [0, HALF_N)
    // decode (b<16, i, j, c4), c4 fastest
    const int c4 = t & (C4 - 1);
    const int j  = (t >> 4) & (WO - 1);
    const int i  = (t >> 10) & (HO - 1);
    const int b  = t >> 16;                                 // 0..15

    const int baseA = ((b * HH + 2 * i) * WW + 2 * j) * C4 + c4;
    const int baseB = baseA + POOL_HALF;                    // b+16

    // 10 independent loads, all issued before any use.
    const v4 a00 = __builtin_nontemporal_load(&pool[baseA]);
    const v4 a01 = __builtin_nontemporal_load(&pool[baseA + C4]);
    const v4 a10 = __builtin_nontemporal_load(&pool[baseA + WC4]);
    const v4 a11 = __builtin_nontemporal_load(&pool[baseA + WC4 + C4]);
    const v4 b00 = __builtin_nontemporal_load(&pool[baseB]);
    const v4 b01 = __builtin_nontemporal_load(&pool[baseB + C4]);
    const v4 b10 = __builtin_nontemporal_load(&pool[baseB + WC4]);
    const v4 b11 = __builtin_nontemporal_load(&pool[baseB + WC4 + C4]);
    const v4 vA  = __builtin_nontemporal_load(&input[t]);
    const v4 vB  = __builtin_nontemporal_load(&input[t + HALF_N]);

    const v4 mA = vmax4(vmax4(a00, a01), vmax4(a10, a11));
    const v4 mB = vmax4(vmax4(b00, b01), vmax4(b10, b11));

    __builtin_nontemporal_store(vsel(a00, mA, vA), &out[baseA]);
    __builtin_nontemporal_store(vsel(a01, mA, vA), &out[baseA + C4]);
    __builtin_nontemporal_store(vsel(a10, mA, vA), &out[baseA + WC4]);
    __builtin_nontemporal_store(vsel(a11, mA, vA), &out[baseA + WC4 + C4]);
    __builtin_nontemporal_store(vsel(b00, mB, vB), &out[baseB]);
    __builtin_nontemporal_store(vsel(b01, mB, vB), &out[baseB + C4]);
    __builtin_nontemporal_store(vsel(b10, mB, vB), &out[baseB + WC4]);
    __builtin_nontemporal_store(vsel(b11, mB, vB), &out[baseB + WC4 + C4]);
}

extern "C" void kernel_launch(void* const* d_in, const int* in_sizes, int n_in,
                              void* d_out, int out_size, void* d_ws, size_t ws_size,
                              hipStream_t stream) {
    const v4* input = (const v4*)d_in[0];
    const v4* pool  = (const v4*)d_in[1];
    v4* out = (v4*)d_out;

    const int block = 256;
    const int grid = HALF_N / block;   // 4096 blocks
    unpool2d_kernel<<<grid, block, 0, stream>>>(input, pool, out);
}